// Round 8
// baseline (300.811 us; speedup 1.0000x reference)
//
#include <hip/hip_runtime.h>
#include <hip/hip_bf16.h>
#include <math.h>

// Problem constants
#define Bq  2
#define Sq  2048
#define Hq  1024
#define Nq  16
#define HNq 64
#define Mq  (Bq*Sq)        // 4096 rows
#define H3q (3*Hq)         // 3072

#define LOG2E 1.44269504088896340736f

typedef __attribute__((ext_vector_type(8))) short           short8;
typedef __attribute__((ext_vector_type(4))) short           short4s;
typedef __attribute__((ext_vector_type(8))) unsigned short  ushortx8;
typedef __attribute__((ext_vector_type(4))) unsigned short  ushortx4;
typedef __attribute__((ext_vector_type(4))) float           floatx4;

__device__ __forceinline__ unsigned short f2bf(float f) {
    union { float f; unsigned int u; } x; x.f = f;
    unsigned int r = (x.u + 0x7fffu + ((x.u >> 16) & 1u)) >> 16;
    return (unsigned short)r;
}

// packed fp32x2 -> bf16x2 (v_cvt_pk_bf16_f32 on gfx950); a in low 16 bits
__device__ __forceinline__ unsigned int pkbf(float a, float b) {
    float2 t; t.x = a; t.y = b;
    __hip_bfloat162 h = __float22bfloat162_rn(t);
    union { __hip_bfloat162 h; unsigned int u; } c; c.h = h;
    return c.u;
}

__device__ __forceinline__ float bf2f(unsigned short v) {
    union { unsigned int u; float f; } x; x.u = (unsigned int)v << 16;
    return x.f;
}

// async global->LDS, 16B per lane; LDS dest = wave-uniform base + lane*16
__device__ __forceinline__ void gload16(const unsigned short* g, unsigned short* l) {
    __builtin_amdgcn_global_load_lds(
        (__attribute__((address_space(1))) void*)(unsigned long long)(g),
        (__attribute__((address_space(3))) void*)(unsigned int)(unsigned long long)(l),
        16, 0, 0);
}

// LDS bank swizzle: granule' = granule ^ swz(row mod 16); 2-way max conflict
__device__ __forceinline__ int swz(int r) { return (r ^ (r >> 2)) & 3; }

// ---------------------------------------------------------------------------
// Fused fp32 -> bf16 cast for hidden | W_qkv | W_out (contiguous bf16 dst)
// ---------------------------------------------------------------------------
#define N_HID ((size_t)Mq * Hq)          // 4194304
#define N_HW  (N_HID + (size_t)H3q * Hq) // 7340032
#define N_ALL (N_HW + (size_t)Hq * Hq)   // 8388608

__global__ __launch_bounds__(256) void cvt_all(
    const float* __restrict__ hidden, const float* __restrict__ wqkv,
    const float* __restrict__ wout, unsigned short* __restrict__ dst)
{
    size_t i = ((size_t)blockIdx.x * 256 + threadIdx.x) * 8;
    const float* src;
    if (i < N_HID)      src = hidden + i;
    else if (i < N_HW)  src = wqkv + (i - N_HID);
    else                src = wout + (i - N_HW);
    float4 a = *(const float4*)(src);
    float4 b = *(const float4*)(src + 4);
    union { unsigned int u[4]; ushortx8 s; } o;
    o.u[0] = pkbf(a.x, a.y); o.u[1] = pkbf(a.z, a.w);
    o.u[2] = pkbf(b.x, b.y); o.u[3] = pkbf(b.z, b.w);
    *(ushortx8*)(dst + i) = o.s;
}

// ---------------------------------------------------------------------------
// MFMA GEMM core: 128x128 tile, BK=32, 4 waves each computing 64x64.
// ---------------------------------------------------------------------------
#define TM 128
#define TN 128
#define TK 32

// GEMM1: -> qkv bf16 (Q scaled 1/8*log2e) + V^T global [b,n,d,s]
__global__ __launch_bounds__(256) void gemm_mfma_qkv(
    const unsigned short* __restrict__ A, const unsigned short* __restrict__ Bw,
    const float* __restrict__ bias, unsigned short* __restrict__ qkvC,
    unsigned short* __restrict__ vT, int M, int Nd, int K)
{
    __shared__ unsigned short As[TM][TK];
    __shared__ unsigned short Bs[TN][TK];

    const int tid = threadIdx.x;
    const int w = tid >> 6, lane = tid & 63;
    const int l15 = lane & 15, quad = lane >> 4;
    const int wr = (w & 1) * 64;
    const int wc = (w >> 1) * 64;
    const int row0 = blockIdx.y * TM;
    const int col0 = blockIdx.x * TN;

    const int srow16 = lane >> 2;
    const int sgd    = lane & 3;
    const int sgsrc  = (sgd ^ swz(srow16)) * 8;

    floatx4 acc[4][4];
    #pragma unroll
    for (int i = 0; i < 4; i++)
        #pragma unroll
        for (int j = 0; j < 4; j++) acc[i][j] = (floatx4){0.f,0.f,0.f,0.f};

    const int aswz = swz(l15) * 8;

    for (int k0 = 0; k0 < K; k0 += TK) {
        __syncthreads();
        #pragma unroll
        for (int c = 0; c < 2; c++) {
            int seg = w * 2 + c;
            int r = seg * 16 + srow16;
            gload16(A  + (size_t)(row0 + r) * K + k0 + sgsrc, &As[seg * 16][0]);
            gload16(Bw + (size_t)(col0 + r) * K + k0 + sgsrc, &Bs[seg * 16][0]);
        }
        __syncthreads();

        short8 af[4], bf[4];
        #pragma unroll
        for (int i = 0; i < 4; i++)
            af[i] = *(const short8*)&As[wr + i * 16 + l15][(quad * 8) ^ aswz];
        #pragma unroll
        for (int j = 0; j < 4; j++)
            bf[j] = *(const short8*)&Bs[wc + j * 16 + l15][(quad * 8) ^ aswz];
        #pragma unroll
        for (int i = 0; i < 4; i++)
            #pragma unroll
            for (int j = 0; j < 4; j++)
                acc[i][j] = __builtin_amdgcn_mfma_f32_16x16x32_bf16(af[i], bf[j], acc[i][j], 0, 0, 0);
    }

    #pragma unroll
    for (int i = 0; i < 4; i++) {
        const int rb = row0 + wr + i * 16 + quad * 4;
        const int b  = rb >> 11;
        const int s  = rb & (Sq - 1);
        #pragma unroll
        for (int j = 0; j < 4; j++) {
            const int c = col0 + wc + j * 16 + l15;
            const float bia = bias[c];
            if (c < 2 * Hq) {
                // Q columns: fold 1/sqrt(64) and log2(e) for exp2-softmax
                const float scale = (c < Hq) ? (0.125f * LOG2E) : 1.0f;
                #pragma unroll
                for (int rr = 0; rr < 4; rr++)
                    qkvC[(size_t)(rb + rr) * Nd + c] = f2bf((acc[i][j][rr] + bia) * scale);
            } else {
                const int c2 = c - 2 * Hq;           // n*64+d
                ushortx4 o;
                #pragma unroll
                for (int rr = 0; rr < 4; rr++) o[rr] = f2bf(acc[i][j][rr] + bia);
                *(ushortx4*)&vT[((size_t)(b << 10) + c2) * Sq + s] = o;
            }
        }
    }
}

// GEMM2: x = A*Bw^T + bias + residual -> bf16 (LN reads bf16, stats in fp32)
__global__ __launch_bounds__(256) void gemm_mfma_out(
    const unsigned short* __restrict__ A, const unsigned short* __restrict__ Bw,
    const float* __restrict__ bias, const float* __restrict__ res,
    unsigned short* __restrict__ X, int M, int Nd, int K)
{
    __shared__ unsigned short As[TM][TK];
    __shared__ unsigned short Bs[TN][TK];

    const int tid = threadIdx.x;
    const int w = tid >> 6, lane = tid & 63;
    const int l15 = lane & 15, quad = lane >> 4;
    const int wr = (w & 1) * 64;
    const int wc = (w >> 1) * 64;
    const int row0 = blockIdx.y * TM;
    const int col0 = blockIdx.x * TN;

    const int srow16 = lane >> 2;
    const int sgd    = lane & 3;
    const int sgsrc  = (sgd ^ swz(srow16)) * 8;

    floatx4 acc[4][4];
    #pragma unroll
    for (int i = 0; i < 4; i++)
        #pragma unroll
        for (int j = 0; j < 4; j++) acc[i][j] = (floatx4){0.f,0.f,0.f,0.f};

    const int aswz = swz(l15) * 8;

    for (int k0 = 0; k0 < K; k0 += TK) {
        __syncthreads();
        #pragma unroll
        for (int c = 0; c < 2; c++) {
            int seg = w * 2 + c;
            int r = seg * 16 + srow16;
            gload16(A  + (size_t)(row0 + r) * K + k0 + sgsrc, &As[seg * 16][0]);
            gload16(Bw + (size_t)(col0 + r) * K + k0 + sgsrc, &Bs[seg * 16][0]);
        }
        __syncthreads();

        short8 af[4], bf[4];
        #pragma unroll
        for (int i = 0; i < 4; i++)
            af[i] = *(const short8*)&As[wr + i * 16 + l15][(quad * 8) ^ aswz];
        #pragma unroll
        for (int j = 0; j < 4; j++)
            bf[j] = *(const short8*)&Bs[wc + j * 16 + l15][(quad * 8) ^ aswz];
        #pragma unroll
        for (int i = 0; i < 4; i++)
            #pragma unroll
            for (int j = 0; j < 4; j++)
                acc[i][j] = __builtin_amdgcn_mfma_f32_16x16x32_bf16(af[i], bf[j], acc[i][j], 0, 0, 0);
    }

    #pragma unroll
    for (int i = 0; i < 4; i++) {
        const int rb = row0 + wr + i * 16 + quad * 4;
        #pragma unroll
        for (int j = 0; j < 4; j++) {
            const int c = col0 + wc + j * 16 + l15;
            const float bia = bias[c];
            #pragma unroll
            for (int rr = 0; rr < 4; rr++) {
                X[(size_t)(rb + rr) * Nd + c] =
                    f2bf(acc[i][j][rr] + bia + res[(size_t)(rb + rr) * Nd + c]);
            }
        }
    }
}

// ---------------------------------------------------------------------------
// Split-K transposed-softmax MFMA flash attention, 32 queries per wave.
// 512 threads = 8 waves = 2 key-groups x 4 waves; each wave owns 2 q-subtiles
// (qtile = 128 queries/block). K fragment read once -> 2 S^T MFMAs; V fragment
// read once -> 2 PV MFMAs: LDS bytes and staging VALU per query HALVED vs 16q.
// Streaming exp2 softmax (no running max), per-lane partial l.
// ---------------------------------------------------------------------------
#define KTILES 16                     // 64-key tiles per group
#define KS_BYTES  (2 * 64 * 72 * 2)   // 18432
#define VT_BYTES  (2 * 64 * 64 * 2)   // 16384
#define SMEM_BYTES (KS_BYTES + VT_BYTES + 2 * 64 * 4)  // + masks = 35328

__global__ __launch_bounds__(512, 4) void attn_mfma(
    const unsigned short* __restrict__ qkv, const unsigned short* __restrict__ vT,
    const float* __restrict__ mask, unsigned short* __restrict__ ctx)
{
    __shared__ __align__(16) char smem[SMEM_BYTES];

    const int tid  = threadIdx.x;
    const int w    = tid >> 6;        // 0..7
    const int g    = w >> 2;          // key-group 0/1
    const int wg   = w & 3;           // q-subtile row within group
    const int lane = tid & 63;
    const int l15  = lane & 15;
    const int quad = lane >> 4;
    const int tg   = tid & 255;       // thread within group

    unsigned short* Ks    = (unsigned short*)smem + g * (64 * 72);
    unsigned short* Vt    = (unsigned short*)(smem + KS_BYTES) + g * (64 * 64);
    float*          maskS = (float*)(smem + KS_BYTES + VT_BYTES) + g * 64;
    float*          mergeO = (float*)smem;   // aliased after final barrier

    const int qtile = blockIdx.x;     // 0..15 (128 q each)
    const int bn    = blockIdx.y;
    const int n     = bn & 15;
    const int b     = bn >> 4;

    const int qoff = n * HNq;
    const int koff = Hq + n * HNq;

    // Q B-fragments for both subtiles (n=l15 -> query row, k=quad*8+j)
    short8 qfrag[2][2];
    #pragma unroll
    for (int sub = 0; sub < 2; sub++) {
        const int qrow = qtile * 128 + sub * 64 + wg * 16 + l15;
        const unsigned short* qp = qkv + (size_t)(b * Sq + qrow) * H3q + qoff + quad * 8;
        qfrag[sub][0] = *(const short8*)(qp);
        qfrag[sub][1] = *(const short8*)(qp + 32);
    }

    floatx4 oacc[2][4];   // O^T per subtile: d = dt*16 + quad*4 + r, q = l15
    #pragma unroll
    for (int sub = 0; sub < 2; sub++)
        #pragma unroll
        for (int dt = 0; dt < 4; dt++) oacc[sub][dt] = (floatx4){0.f,0.f,0.f,0.f};
    float l_part[2] = {0.f, 0.f};

    const int stg_k  = tg >> 2;          // 0..63
    const int stg_c0 = (tg & 3) * 16;
    const unsigned short* vbase = vT + (size_t)(b * Nq + n) * HNq * Sq;

    // V staging geometry (granule-XOR swizzle by d&7)
    const int vd0 = tg >> 3,        vg0 = tg & 7;
    const int vd1 = 32 + (tg >> 3), vg1 = tg & 7;

    const int kbase = g * (KTILES * 64);

    // software pipeline: prefetch tile kt+1 during compute of kt
    ushortx8 kreg0, kreg1, vreg0, vreg1;
    float mreg;
    {
        const unsigned short* ks0 = qkv + (size_t)(b * Sq + kbase + stg_k) * H3q + koff + stg_c0;
        kreg0 = *(const ushortx8*)(ks0);
        kreg1 = *(const ushortx8*)(ks0 + 8);
        vreg0 = *(const ushortx8*)(vbase + (size_t)vd0 * Sq + kbase + vg0 * 8);
        vreg1 = *(const ushortx8*)(vbase + (size_t)vd1 * Sq + kbase + vg1 * 8);
        mreg  = (tg < 64) ? mask[(size_t)b * Sq + kbase + tg] * LOG2E : 0.f;
    }

    for (int kt = 0; kt < KTILES; kt++) {
        __syncthreads();
        // store staged tile to LDS
        *(ushortx8*)&Ks[stg_k * 72 + stg_c0]     = kreg0;
        *(ushortx8*)&Ks[stg_k * 72 + stg_c0 + 8] = kreg1;
        *(ushortx8*)&Vt[vd0 * 64 + ((vg0 ^ (vd0 & 7)) * 8)] = vreg0;
        *(ushortx8*)&Vt[vd1 * 64 + ((vg1 ^ (vd1 & 7)) * 8)] = vreg1;
        if (tg < 64) maskS[tg] = mreg;
        __syncthreads();

        // prefetch next tile
        if (kt + 1 < KTILES) {
            const int nk0 = kbase + (kt + 1) * 64;
            const unsigned short* ks0 = qkv + (size_t)(b * Sq + nk0 + stg_k) * H3q + koff + stg_c0;
            kreg0 = *(const ushortx8*)(ks0);
            kreg1 = *(const ushortx8*)(ks0 + 8);
            vreg0 = *(const ushortx8*)(vbase + (size_t)vd0 * Sq + nk0 + vg0 * 8);
            vreg1 = *(const ushortx8*)(vbase + (size_t)vd1 * Sq + nk0 + vg1 * 8);
            mreg  = (tg < 64) ? mask[(size_t)b * Sq + nk0 + tg] * LOG2E : 0.f;
        }

        // ---- S^T = K Q^T for both subtiles; each af read feeds 2 MFMAs
        floatx4 sacc[2][4];
        #pragma unroll
        for (int sub = 0; sub < 2; sub++)
            #pragma unroll
            for (int ct = 0; ct < 4; ct++) sacc[sub][ct] = (floatx4){0.f,0.f,0.f,0.f};
        #pragma unroll
        for (int ks = 0; ks < 2; ks++) {
            #pragma unroll
            for (int ct = 0; ct < 4; ct++) {
                short8 af = *(const short8*)&Ks[(ct * 16 + l15) * 72 + ks * 32 + quad * 8];
                sacc[0][ct] = __builtin_amdgcn_mfma_f32_16x16x32_bf16(af, qfrag[0][ks], sacc[0][ct], 0, 0, 0);
                sacc[1][ct] = __builtin_amdgcn_mfma_f32_16x16x32_bf16(af, qfrag[1][ks], sacc[1][ct], 0, 0, 0);
            }
        }

        // ---- streaming softmax fused with P^T pack, per subtile
        short8 pf[2][2];  // pf[sub][ks][(ct&1)*4+r] = P(key=16ct+4quad+r)
        #pragma unroll
        for (int sub = 0; sub < 2; sub++) {
            #pragma unroll
            for (int ks = 0; ks < 2; ks++) {
                union { unsigned int u[4]; short8 s; } pk;
                #pragma unroll
                for (int h = 0; h < 2; h++) {
                    const int ct = ks * 2 + h;
                    float4 mkv = *(const float4*)&maskS[ct * 16 + quad * 4];
                    float p0 = exp2f(sacc[sub][ct][0] + mkv.x);
                    float p1 = exp2f(sacc[sub][ct][1] + mkv.y);
                    float p2 = exp2f(sacc[sub][ct][2] + mkv.z);
                    float p3 = exp2f(sacc[sub][ct][3] + mkv.w);
                    l_part[sub] += (p0 + p1) + (p2 + p3);
                    pk.u[h * 2]     = pkbf(p0, p1);
                    pk.u[h * 2 + 1] = pkbf(p2, p3);
                }
                pf[sub][ks] = pk.s;
            }
        }

        // ---- O^T += V^T P^T; each vf read feeds 2 MFMAs
        #pragma unroll
        for (int ks = 0; ks < 2; ks++) {
            const int c0 = (((4 * ks +     (quad >> 1)) ^ (l15 & 7)) * 8) + (quad & 1) * 4;
            const int c1 = (((4 * ks + 2 + (quad >> 1)) ^ (l15 & 7)) * 8) + (quad & 1) * 4;
            #pragma unroll
            for (int dt = 0; dt < 4; dt++) {
                const int d = dt * 16 + l15;
                short4s lo = *(const short4s*)&Vt[d * 64 + c0];
                short4s hi = *(const short4s*)&Vt[d * 64 + c1];
                short8 vf = __builtin_shufflevector(lo, hi, 0, 1, 2, 3, 4, 5, 6, 7);
                oacc[0][dt] = __builtin_amdgcn_mfma_f32_16x16x32_bf16(vf, pf[0][ks], oacc[0][dt], 0, 0, 0);
                oacc[1][dt] = __builtin_amdgcn_mfma_f32_16x16x32_bf16(vf, pf[1][ks], oacc[1][dt], 0, 0, 0);
            }
        }
    }

    // ---- two-phase merge of group 1 into group 0 (20KB scratch reused)
    #pragma unroll
    for (int sub = 0; sub < 2; sub++) {
        __syncthreads();
        if (g == 1) {
            float* dstm = mergeO + (size_t)(wg * 64 + lane) * 20;
            #pragma unroll
            for (int dt = 0; dt < 4; dt++) *(floatx4*)(dstm + dt * 4) = oacc[sub][dt];
            dstm[16] = l_part[sub];
        }
        __syncthreads();
        if (g == 0) {
            const float* srcm = mergeO + (size_t)(wg * 64 + lane) * 20;
            #pragma unroll
            for (int dt = 0; dt < 4; dt++) oacc[sub][dt] += *(const floatx4*)(srcm + dt * 4);
            l_part[sub] += srcm[16];
        }
    }

    if (g == 0) {
        #pragma unroll
        for (int sub = 0; sub < 2; sub++) {
            float l_i = l_part[sub];
            l_i += __shfl_xor(l_i, 16, 64);
            l_i += __shfl_xor(l_i, 32, 64);
            const float inv = 1.0f / l_i;
            const int qrow = qtile * 128 + sub * 64 + wg * 16 + l15;
            #pragma unroll
            for (int dt = 0; dt < 4; dt++) {
                union { unsigned int u[2]; ushortx4 s; } o;
                o.u[0] = pkbf(oacc[sub][dt][0] * inv, oacc[sub][dt][1] * inv);
                o.u[1] = pkbf(oacc[sub][dt][2] * inv, oacc[sub][dt][3] * inv);
                const int col = n * HNq + dt * 16 + quad * 4;
                *(ushortx4*)&ctx[(size_t)(b * Sq + qrow) * Hq + col] = o.s;
            }
        }
    }
}

// ---------------------------------------------------------------------------
// Row LayerNorm over H=1024, bf16 input, fp32 stats, fp32 output.
// ---------------------------------------------------------------------------
__global__ __launch_bounds__(256) void ln_kernel(
    const unsigned short* __restrict__ X, const float* __restrict__ gamma,
    const float* __restrict__ beta, float* __restrict__ out)
{
    const int row = blockIdx.x;
    const int c0  = threadIdx.x * 4;
    ushortx4 xv = *(const ushortx4*)(X + (size_t)row * Hq + c0);
    float vals[4];
    float lsum = 0.0f;
    #pragma unroll
    for (int i = 0; i < 4; i++) { vals[i] = bf2f(xv[i]); lsum += vals[i]; }

    __shared__ float red[8];
    const int wid = threadIdx.x >> 6, lane = threadIdx.x & 63;

    float s = lsum;
    #pragma unroll
    for (int off = 32; off >= 1; off >>= 1) s += __shfl_xor(s, off, 64);
    if (lane == 0) red[wid] = s;
    __syncthreads();
    const float mean = (red[0] + red[1] + red[2] + red[3]) * (1.0f / Hq);

    float v = 0.0f;
    #pragma unroll
    for (int i = 0; i < 4; i++) { float d = vals[i] - mean; v += d * d; }
    #pragma unroll
    for (int off = 32; off >= 1; off >>= 1) v += __shfl_xor(v, off, 64);
    if (lane == 0) red[4 + wid] = v;
    __syncthreads();
    const float var  = (red[4] + red[5] + red[6] + red[7]) * (1.0f / Hq);
    const float rstd = rsqrtf(var + 1e-12f);

    float4 gm = *(const float4*)(gamma + c0);
    float4 bt = *(const float4*)(beta + c0);
    float4 o;
    o.x = (vals[0] - mean) * rstd * gm.x + bt.x;
    o.y = (vals[1] - mean) * rstd * gm.y + bt.y;
    o.z = (vals[2] - mean) * rstd * gm.z + bt.z;
    o.w = (vals[3] - mean) * rstd * gm.w + bt.w;
    *(float4*)(out + (size_t)row * Hq + c0) = o;
}

// ---------------------------------------------------------------------------
extern "C" void kernel_launch(void* const* d_in, const int* in_sizes, int n_in,
                              void* d_out, int out_size, void* d_ws, size_t ws_size,
                              hipStream_t stream)
{
    const float* hidden = (const float*)d_in[0];
    const float* mask   = (const float*)d_in[1];
    const float* W_qkv  = (const float*)d_in[2];
    const float* b_qkv  = (const float*)d_in[3];
    const float* W_out  = (const float*)d_in[4];
    const float* b_out  = (const float*)d_in[5];
    const float* gamma  = (const float*)d_in[6];
    const float* beta   = (const float*)d_in[7];
    float* out = (float*)d_out;

    const size_t nHid  = (size_t)Mq * Hq;        // 4 M
    const size_t nWq   = (size_t)H3q * Hq;       // 3 M
    const size_t nWo   = (size_t)Hq * Hq;        // 1 M
    const size_t nQKV  = (size_t)Mq * H3q;       // 12 M
    const size_t nVT   = (size_t)Bq * Hq * Sq;   // 4 M
    const size_t nCtx  = (size_t)Mq * Hq;        // 4 M

    unsigned short* hidden_bf = (unsigned short*)d_ws;
    unsigned short* Wqkv_bf   = hidden_bf + nHid;
    unsigned short* Wout_bf   = Wqkv_bf + nWq;
    unsigned short* qkv_bf    = Wout_bf + nWo;
    unsigned short* vT        = qkv_bf + nQKV;
    unsigned short* ctx_bf    = vT + nVT;
    unsigned short* x_bf      = ctx_bf + nCtx;

    dim3 blk(256);

    // 0) fused fp32 -> bf16 cast (hidden | W_qkv | W_out contiguous dst)
    cvt_all<<<dim3((int)(N_ALL / 2048)), blk, 0, stream>>>(
        hidden, W_qkv, W_out, hidden_bf);

    // 1) QKV projection (MFMA) -> qkv bf16 (Q/K) + V^T
    gemm_mfma_qkv<<<dim3(H3q / TN, Mq / TM), blk, 0, stream>>>(
        hidden_bf, Wqkv_bf, b_qkv, qkv_bf, vT, Mq, H3q, Hq);

    // 2) Split-K MFMA flash attention (32 q/wave) -> ctx bf16
    attn_mfma<<<dim3(Sq / 128, Bq * Nq), dim3(512), 0, stream>>>(
        qkv_bf, vT, mask, ctx_bf);

    // 3) Output projection (MFMA) + bias + residual -> x bf16
    gemm_mfma_out<<<dim3(Hq / TN, Mq / TM), blk, 0, stream>>>(
        ctx_bf, Wout_bf, b_out, hidden, x_bf, Mq, Hq, Hq);

    // 4) LayerNorm: bf16 x -> fp32 out
    ln_kernel<<<dim3(Mq), blk, 0, stream>>>(x_bf, gamma, beta, out);
}

// Round 9
// 240.527 us; speedup vs baseline: 1.2506x; 1.2506x over previous
//
#include <hip/hip_runtime.h>
#include <hip/hip_bf16.h>
#include <math.h>

// Problem constants
#define Bq  2
#define Sq  2048
#define Hq  1024
#define Nq  16
#define HNq 64
#define Mq  (Bq*Sq)        // 4096 rows
#define H3q (3*Hq)         // 3072

#define LOG2E 1.44269504088896340736f

typedef __attribute__((ext_vector_type(8))) short           short8;
typedef __attribute__((ext_vector_type(4))) short           short4s;
typedef __attribute__((ext_vector_type(8))) unsigned short  ushortx8;
typedef __attribute__((ext_vector_type(4))) unsigned short  ushortx4;
typedef __attribute__((ext_vector_type(4))) float           floatx4;

__device__ __forceinline__ unsigned short f2bf(float f) {
    union { float f; unsigned int u; } x; x.f = f;
    unsigned int r = (x.u + 0x7fffu + ((x.u >> 16) & 1u)) >> 16;
    return (unsigned short)r;
}

// packed fp32x2 -> bf16x2 (v_cvt_pk_bf16_f32 on gfx950); a in low 16 bits
__device__ __forceinline__ unsigned int pkbf(float a, float b) {
    float2 t; t.x = a; t.y = b;
    __hip_bfloat162 h = __float22bfloat162_rn(t);
    union { __hip_bfloat162 h; unsigned int u; } c; c.h = h;
    return c.u;
}

__device__ __forceinline__ float bf2f(unsigned short v) {
    union { unsigned int u; float f; } x; x.u = (unsigned int)v << 16;
    return x.f;
}

// async global->LDS, 16B per lane; LDS dest = wave-uniform base + lane*16
__device__ __forceinline__ void gload16(const unsigned short* g, unsigned short* l) {
    __builtin_amdgcn_global_load_lds(
        (__attribute__((address_space(1))) void*)(unsigned long long)(g),
        (__attribute__((address_space(3))) void*)(unsigned int)(unsigned long long)(l),
        16, 0, 0);
}

// LDS bank swizzle: granule' = granule ^ swz(row mod 16); 2-way max conflict
__device__ __forceinline__ int swz(int r) { return (r ^ (r >> 2)) & 3; }

// ---------------------------------------------------------------------------
// Fused fp32 -> bf16 cast for hidden | W_qkv | W_out (contiguous bf16 dst)
// ---------------------------------------------------------------------------
#define N_HID ((size_t)Mq * Hq)          // 4194304
#define N_HW  (N_HID + (size_t)H3q * Hq) // 7340032
#define N_ALL (N_HW + (size_t)Hq * Hq)   // 8388608

__global__ __launch_bounds__(256) void cvt_all(
    const float* __restrict__ hidden, const float* __restrict__ wqkv,
    const float* __restrict__ wout, unsigned short* __restrict__ dst)
{
    size_t i = ((size_t)blockIdx.x * 256 + threadIdx.x) * 8;
    const float* src;
    if (i < N_HID)      src = hidden + i;
    else if (i < N_HW)  src = wqkv + (i - N_HID);
    else                src = wout + (i - N_HW);
    float4 a = *(const float4*)(src);
    float4 b = *(const float4*)(src + 4);
    union { unsigned int u[4]; ushortx8 s; } o;
    o.u[0] = pkbf(a.x, a.y); o.u[1] = pkbf(a.z, a.w);
    o.u[2] = pkbf(b.x, b.y); o.u[3] = pkbf(b.z, b.w);
    *(ushortx8*)(dst + i) = o.s;
}

// ---------------------------------------------------------------------------
// MFMA GEMM core: 128x128 tile, BK=32, 4 waves each computing 64x64.
// ---------------------------------------------------------------------------
#define TM 128
#define TN 128
#define TK 32

// GEMM1: -> qkv bf16 (Q scaled 1/8*log2e) + V^T global [b,n,d,s]
__global__ __launch_bounds__(256) void gemm_mfma_qkv(
    const unsigned short* __restrict__ A, const unsigned short* __restrict__ Bw,
    const float* __restrict__ bias, unsigned short* __restrict__ qkvC,
    unsigned short* __restrict__ vT, int M, int Nd, int K)
{
    __shared__ unsigned short As[TM][TK];
    __shared__ unsigned short Bs[TN][TK];

    const int tid = threadIdx.x;
    const int w = tid >> 6, lane = tid & 63;
    const int l15 = lane & 15, quad = lane >> 4;
    const int wr = (w & 1) * 64;
    const int wc = (w >> 1) * 64;
    const int row0 = blockIdx.y * TM;
    const int col0 = blockIdx.x * TN;

    const int srow16 = lane >> 2;
    const int sgd    = lane & 3;
    const int sgsrc  = (sgd ^ swz(srow16)) * 8;

    floatx4 acc[4][4];
    #pragma unroll
    for (int i = 0; i < 4; i++)
        #pragma unroll
        for (int j = 0; j < 4; j++) acc[i][j] = (floatx4){0.f,0.f,0.f,0.f};

    const int aswz = swz(l15) * 8;

    for (int k0 = 0; k0 < K; k0 += TK) {
        __syncthreads();
        #pragma unroll
        for (int c = 0; c < 2; c++) {
            int seg = w * 2 + c;
            int r = seg * 16 + srow16;
            gload16(A  + (size_t)(row0 + r) * K + k0 + sgsrc, &As[seg * 16][0]);
            gload16(Bw + (size_t)(col0 + r) * K + k0 + sgsrc, &Bs[seg * 16][0]);
        }
        __syncthreads();

        short8 af[4], bf[4];
        #pragma unroll
        for (int i = 0; i < 4; i++)
            af[i] = *(const short8*)&As[wr + i * 16 + l15][(quad * 8) ^ aswz];
        #pragma unroll
        for (int j = 0; j < 4; j++)
            bf[j] = *(const short8*)&Bs[wc + j * 16 + l15][(quad * 8) ^ aswz];
        #pragma unroll
        for (int i = 0; i < 4; i++)
            #pragma unroll
            for (int j = 0; j < 4; j++)
                acc[i][j] = __builtin_amdgcn_mfma_f32_16x16x32_bf16(af[i], bf[j], acc[i][j], 0, 0, 0);
    }

    #pragma unroll
    for (int i = 0; i < 4; i++) {
        const int rb = row0 + wr + i * 16 + quad * 4;
        const int b  = rb >> 11;
        const int s  = rb & (Sq - 1);
        #pragma unroll
        for (int j = 0; j < 4; j++) {
            const int c = col0 + wc + j * 16 + l15;
            const float bia = bias[c];
            if (c < 2 * Hq) {
                // Q columns: fold 1/sqrt(64) and log2(e) for exp2-softmax
                const float scale = (c < Hq) ? (0.125f * LOG2E) : 1.0f;
                #pragma unroll
                for (int rr = 0; rr < 4; rr++)
                    qkvC[(size_t)(rb + rr) * Nd + c] = f2bf((acc[i][j][rr] + bia) * scale);
            } else {
                const int c2 = c - 2 * Hq;           // n*64+d
                ushortx4 o;
                #pragma unroll
                for (int rr = 0; rr < 4; rr++) o[rr] = f2bf(acc[i][j][rr] + bia);
                *(ushortx4*)&vT[((size_t)(b << 10) + c2) * Sq + s] = o;
            }
        }
    }
}

// GEMM2: x = A*Bw^T + bias + residual -> bf16 (LN reads bf16, stats in fp32)
__global__ __launch_bounds__(256) void gemm_mfma_out(
    const unsigned short* __restrict__ A, const unsigned short* __restrict__ Bw,
    const float* __restrict__ bias, const float* __restrict__ res,
    unsigned short* __restrict__ X, int M, int Nd, int K)
{
    __shared__ unsigned short As[TM][TK];
    __shared__ unsigned short Bs[TN][TK];

    const int tid = threadIdx.x;
    const int w = tid >> 6, lane = tid & 63;
    const int l15 = lane & 15, quad = lane >> 4;
    const int wr = (w & 1) * 64;
    const int wc = (w >> 1) * 64;
    const int row0 = blockIdx.y * TM;
    const int col0 = blockIdx.x * TN;

    const int srow16 = lane >> 2;
    const int sgd    = lane & 3;
    const int sgsrc  = (sgd ^ swz(srow16)) * 8;

    floatx4 acc[4][4];
    #pragma unroll
    for (int i = 0; i < 4; i++)
        #pragma unroll
        for (int j = 0; j < 4; j++) acc[i][j] = (floatx4){0.f,0.f,0.f,0.f};

    const int aswz = swz(l15) * 8;

    for (int k0 = 0; k0 < K; k0 += TK) {
        __syncthreads();
        #pragma unroll
        for (int c = 0; c < 2; c++) {
            int seg = w * 2 + c;
            int r = seg * 16 + srow16;
            gload16(A  + (size_t)(row0 + r) * K + k0 + sgsrc, &As[seg * 16][0]);
            gload16(Bw + (size_t)(col0 + r) * K + k0 + sgsrc, &Bs[seg * 16][0]);
        }
        __syncthreads();

        short8 af[4], bf[4];
        #pragma unroll
        for (int i = 0; i < 4; i++)
            af[i] = *(const short8*)&As[wr + i * 16 + l15][(quad * 8) ^ aswz];
        #pragma unroll
        for (int j = 0; j < 4; j++)
            bf[j] = *(const short8*)&Bs[wc + j * 16 + l15][(quad * 8) ^ aswz];
        #pragma unroll
        for (int i = 0; i < 4; i++)
            #pragma unroll
            for (int j = 0; j < 4; j++)
                acc[i][j] = __builtin_amdgcn_mfma_f32_16x16x32_bf16(af[i], bf[j], acc[i][j], 0, 0, 0);
    }

    #pragma unroll
    for (int i = 0; i < 4; i++) {
        const int rb = row0 + wr + i * 16 + quad * 4;
        #pragma unroll
        for (int j = 0; j < 4; j++) {
            const int c = col0 + wc + j * 16 + l15;
            const float bia = bias[c];
            #pragma unroll
            for (int rr = 0; rr < 4; rr++) {
                X[(size_t)(rb + rr) * Nd + c] =
                    f2bf(acc[i][j][rr] + bia + res[(size_t)(rb + rr) * Nd + c]);
            }
        }
    }
}

// ---------------------------------------------------------------------------
// Grid-split-K transposed-softmax MFMA flash attention (R5 body, z-split x2).
// 256 threads = 4 waves, 16 q/wave. blockIdx.z selects keys [z*1024, +1024).
// Streaming exp2 softmax (no running max) => halves combine by plain addition:
// each half writes un-normalized O (bf16) + per-query l; attn_merge normalizes.
// Grid 2048 blocks -> 8 blocks/CU (LDS 17.7KB, ~64 VGPR) = full wave slots.
// ---------------------------------------------------------------------------
#define KTILES 16   // 64-key tiles per z-half
#define PADW 72     // Ks row stride (bf16)

__global__ __launch_bounds__(256) void attn_mfma(
    const unsigned short* __restrict__ qkv, const unsigned short* __restrict__ vT,
    const float* __restrict__ mask, unsigned short* __restrict__ Opart,
    float* __restrict__ Lpart)
{
    __shared__ unsigned short Ks[64][PADW];   // [key][d]
    __shared__ unsigned short Vt[64][64];     // [d][key], granule-XOR swizzled
    __shared__ float maskS[64];

    const int tid  = threadIdx.x;
    const int w    = tid >> 6;
    const int lane = tid & 63;
    const int l15  = lane & 15;
    const int quad = lane >> 4;

    const int qtile = blockIdx.x;
    const int bn    = blockIdx.y;
    const int z     = blockIdx.z;
    const int n     = bn & 15;
    const int b     = bn >> 4;

    const int qoff = n * HNq;
    const int koff = Hq + n * HNq;
    const int kbase = z * (KTILES * 64);

    // Q B-fragment (n=l15 -> query row, k=quad*8+j) held for whole kernel
    const int qrow = qtile * 64 + w * 16 + l15;
    short8 qfrag[2];
    {
        const unsigned short* qp = qkv + (size_t)(b * Sq + qrow) * H3q + qoff + quad * 8;
        qfrag[0] = *(const short8*)(qp);
        qfrag[1] = *(const short8*)(qp + 32);
    }

    floatx4 oacc[4];   // O^T: d = dt*16 + quad*4 + r, q = l15
    #pragma unroll
    for (int dt = 0; dt < 4; dt++) oacc[dt] = (floatx4){0.f,0.f,0.f,0.f};
    float l_part = 0.f;   // per-lane partial sum of P

    const int stg_k  = tid >> 2;          // 0..63
    const int stg_c0 = (tid & 3) * 16;
    const unsigned short* vbase = vT + (size_t)(b * Nq + n) * HNq * Sq;

    // V staging geometry (granule-XOR swizzle by d&7)
    const int vd0 = tid >> 3,        vg0 = tid & 7;
    const int vd1 = 32 + (tid >> 3), vg1 = tid & 7;

    // software pipeline: prefetch tile kt+1 during compute of kt
    ushortx8 kreg0, kreg1, vreg0, vreg1;
    float mreg;
    {
        const unsigned short* ks0 = qkv + (size_t)(b * Sq + kbase + stg_k) * H3q + koff + stg_c0;
        kreg0 = *(const ushortx8*)(ks0);
        kreg1 = *(const ushortx8*)(ks0 + 8);
        vreg0 = *(const ushortx8*)(vbase + (size_t)vd0 * Sq + kbase + vg0 * 8);
        vreg1 = *(const ushortx8*)(vbase + (size_t)vd1 * Sq + kbase + vg1 * 8);
        mreg  = (tid < 64) ? mask[(size_t)b * Sq + kbase + tid] * LOG2E : 0.f;
    }

    for (int kt = 0; kt < KTILES; kt++) {
        __syncthreads();
        // store staged tile to LDS
        *(ushortx8*)&Ks[stg_k][stg_c0]     = kreg0;
        *(ushortx8*)&Ks[stg_k][stg_c0 + 8] = kreg1;
        *(ushortx8*)&Vt[vd0][(vg0 ^ (vd0 & 7)) * 8] = vreg0;
        *(ushortx8*)&Vt[vd1][(vg1 ^ (vd1 & 7)) * 8] = vreg1;
        if (tid < 64) maskS[tid] = mreg;
        __syncthreads();

        // prefetch next tile
        if (kt + 1 < KTILES) {
            const int nk0 = kbase + (kt + 1) * 64;
            const unsigned short* ks0 = qkv + (size_t)(b * Sq + nk0 + stg_k) * H3q + koff + stg_c0;
            kreg0 = *(const ushortx8*)(ks0);
            kreg1 = *(const ushortx8*)(ks0 + 8);
            vreg0 = *(const ushortx8*)(vbase + (size_t)vd0 * Sq + nk0 + vg0 * 8);
            vreg1 = *(const ushortx8*)(vbase + (size_t)vd1 * Sq + nk0 + vg1 * 8);
            mreg  = (tid < 64) ? mask[(size_t)b * Sq + nk0 + tid] * LOG2E : 0.f;
        }

        // ---- S^T = K Q^T : sacc[ct] holds keys ct*16+quad*4+r for query l15
        floatx4 sacc[4];
        #pragma unroll
        for (int ct = 0; ct < 4; ct++) sacc[ct] = (floatx4){0.f,0.f,0.f,0.f};
        #pragma unroll
        for (int ks = 0; ks < 2; ks++) {
            #pragma unroll
            for (int ct = 0; ct < 4; ct++) {
                short8 af = *(const short8*)&Ks[ct * 16 + l15][ks * 32 + quad * 8];
                sacc[ct] = __builtin_amdgcn_mfma_f32_16x16x32_bf16(af, qfrag[ks], sacc[ct], 0, 0, 0);
            }
        }

        // ---- streaming softmax fused with P^T pack
        short8 pf[2];   // pf[ks][(ct&1)*4+r] = P(key=16ct+4quad+r, q=l15)
        #pragma unroll
        for (int ks = 0; ks < 2; ks++) {
            union { unsigned int u[4]; short8 s; } pk;
            #pragma unroll
            for (int h = 0; h < 2; h++) {
                const int ct = ks * 2 + h;
                float4 mkv = *(const float4*)&maskS[ct * 16 + quad * 4];
                float p0 = exp2f(sacc[ct][0] + mkv.x);
                float p1 = exp2f(sacc[ct][1] + mkv.y);
                float p2 = exp2f(sacc[ct][2] + mkv.z);
                float p3 = exp2f(sacc[ct][3] + mkv.w);
                l_part += (p0 + p1) + (p2 + p3);
                pk.u[h * 2]     = pkbf(p0, p1);
                pk.u[h * 2 + 1] = pkbf(p2, p3);
            }
            pf[ks] = pk.s;
        }

        // ---- O^T += V^T P^T  (permuted k-slots; A = V^T from swizzled LDS)
        #pragma unroll
        for (int ks = 0; ks < 2; ks++) {
            const int c0 = (((4 * ks +     (quad >> 1)) ^ (l15 & 7)) * 8) + (quad & 1) * 4;
            const int c1 = (((4 * ks + 2 + (quad >> 1)) ^ (l15 & 7)) * 8) + (quad & 1) * 4;
            #pragma unroll
            for (int dt = 0; dt < 4; dt++) {
                const int d = dt * 16 + l15;
                short4s lo = *(const short4s*)&Vt[d][c0];
                short4s hi = *(const short4s*)&Vt[d][c1];
                short8 vf = __builtin_shufflevector(lo, hi, 0, 1, 2, 3, 4, 5, 6, 7);
                oacc[dt] = __builtin_amdgcn_mfma_f32_16x16x32_bf16(vf, pf[ks], oacc[dt], 0, 0, 0);
            }
        }
    }

    // ---- epilogue: write un-normalized partial O (bf16) + per-query l
    float l_i = l_part;
    l_i += __shfl_xor(l_i, 16, 64);
    l_i += __shfl_xor(l_i, 32, 64);
    if (quad == 0)
        Lpart[(size_t)z * Mq * Nq + (size_t)(b * Sq + qrow) * Nq + n] = l_i;

    unsigned short* Ow = Opart + (size_t)z * Mq * Hq;
    #pragma unroll
    for (int dt = 0; dt < 4; dt++) {
        union { unsigned int u[2]; ushortx4 s; } o;
        o.u[0] = pkbf(oacc[dt][0], oacc[dt][1]);
        o.u[1] = pkbf(oacc[dt][2], oacc[dt][3]);
        const int col = n * HNq + dt * 16 + quad * 4;
        *(ushortx4*)&Ow[(size_t)(b * Sq + qrow) * Hq + col] = o.s;
    }
}

// ---------------------------------------------------------------------------
// Merge the two split-K halves: ctx = (O0 + O1) / (l0 + l1), bf16 out.
// ---------------------------------------------------------------------------
__global__ __launch_bounds__(256) void attn_merge(
    const unsigned short* __restrict__ Opart, const float* __restrict__ Lpart,
    unsigned short* __restrict__ ctx)
{
    const size_t idx = ((size_t)blockIdx.x * 256 + threadIdx.x) * 4;
    const int row = (int)(idx >> 10);          // b*Sq + s
    const int n   = ((int)idx >> 6) & 15;
    const float l = Lpart[(size_t)row * Nq + n]
                  + Lpart[(size_t)Mq * Nq + (size_t)row * Nq + n];
    const float inv = 1.0f / l;
    ushortx4 a = *(const ushortx4*)(Opart + idx);
    ushortx4 c = *(const ushortx4*)(Opart + (size_t)Mq * Hq + idx);
    union { unsigned int u[2]; ushortx4 s; } o;
    o.u[0] = pkbf((bf2f(a[0]) + bf2f(c[0])) * inv, (bf2f(a[1]) + bf2f(c[1])) * inv);
    o.u[1] = pkbf((bf2f(a[2]) + bf2f(c[2])) * inv, (bf2f(a[3]) + bf2f(c[3])) * inv);
    *(ushortx4*)(ctx + idx) = o.s;
}

// ---------------------------------------------------------------------------
// Row LayerNorm over H=1024, bf16 input, fp32 stats, fp32 output.
// ---------------------------------------------------------------------------
__global__ __launch_bounds__(256) void ln_kernel(
    const unsigned short* __restrict__ X, const float* __restrict__ gamma,
    const float* __restrict__ beta, float* __restrict__ out)
{
    const int row = blockIdx.x;
    const int c0  = threadIdx.x * 4;
    ushortx4 xv = *(const ushortx4*)(X + (size_t)row * Hq + c0);
    float vals[4];
    float lsum = 0.0f;
    #pragma unroll
    for (int i = 0; i < 4; i++) { vals[i] = bf2f(xv[i]); lsum += vals[i]; }

    __shared__ float red[8];
    const int wid = threadIdx.x >> 6, lane = threadIdx.x & 63;

    float s = lsum;
    #pragma unroll
    for (int off = 32; off >= 1; off >>= 1) s += __shfl_xor(s, off, 64);
    if (lane == 0) red[wid] = s;
    __syncthreads();
    const float mean = (red[0] + red[1] + red[2] + red[3]) * (1.0f / Hq);

    float v = 0.0f;
    #pragma unroll
    for (int i = 0; i < 4; i++) { float d = vals[i] - mean; v += d * d; }
    #pragma unroll
    for (int off = 32; off >= 1; off >>= 1) v += __shfl_xor(v, off, 64);
    if (lane == 0) red[4 + wid] = v;
    __syncthreads();
    const float var  = (red[4] + red[5] + red[6] + red[7]) * (1.0f / Hq);
    const float rstd = rsqrtf(var + 1e-12f);

    float4 gm = *(const float4*)(gamma + c0);
    float4 bt = *(const float4*)(beta + c0);
    float4 o;
    o.x = (vals[0] - mean) * rstd * gm.x + bt.x;
    o.y = (vals[1] - mean) * rstd * gm.y + bt.y;
    o.z = (vals[2] - mean) * rstd * gm.z + bt.z;
    o.w = (vals[3] - mean) * rstd * gm.w + bt.w;
    *(float4*)(out + (size_t)row * Hq + c0) = o;
}

// ---------------------------------------------------------------------------
extern "C" void kernel_launch(void* const* d_in, const int* in_sizes, int n_in,
                              void* d_out, int out_size, void* d_ws, size_t ws_size,
                              hipStream_t stream)
{
    const float* hidden = (const float*)d_in[0];
    const float* mask   = (const float*)d_in[1];
    const float* W_qkv  = (const float*)d_in[2];
    const float* b_qkv  = (const float*)d_in[3];
    const float* W_out  = (const float*)d_in[4];
    const float* b_out  = (const float*)d_in[5];
    const float* gamma  = (const float*)d_in[6];
    const float* beta   = (const float*)d_in[7];
    float* out = (float*)d_out;

    const size_t nHid  = (size_t)Mq * Hq;        // 4 M
    const size_t nWq   = (size_t)H3q * Hq;       // 3 M
    const size_t nWo   = (size_t)Hq * Hq;        // 1 M
    const size_t nQKV  = (size_t)Mq * H3q;       // 12 M
    const size_t nVT   = (size_t)Bq * Hq * Sq;   // 4 M
    const size_t nCtx  = (size_t)Mq * Hq;        // 4 M

    unsigned short* hidden_bf = (unsigned short*)d_ws;
    unsigned short* Wqkv_bf   = hidden_bf + nHid;
    unsigned short* Wout_bf   = Wqkv_bf + nWq;
    unsigned short* qkv_bf    = Wout_bf + nWo;
    unsigned short* vT        = qkv_bf + nQKV;
    unsigned short* ctx_bf    = vT + nVT;
    unsigned short* x_bf      = ctx_bf + nCtx;
    unsigned short* opart     = x_bf + nHid;           // 2 * 4M bf16 = 16 MB
    float*          lpart     = (float*)(opart + 2 * nHid);  // 2*64K floats

    dim3 blk(256);

    // 0) fused fp32 -> bf16 cast (hidden | W_qkv | W_out contiguous dst)
    cvt_all<<<dim3((int)(N_ALL / 2048)), blk, 0, stream>>>(
        hidden, W_qkv, W_out, hidden_bf);

    // 1) QKV projection (MFMA) -> qkv bf16 (Q/K) + V^T
    gemm_mfma_qkv<<<dim3(H3q / TN, Mq / TM), blk, 0, stream>>>(
        hidden_bf, Wqkv_bf, b_qkv, qkv_bf, vT, Mq, H3q, Hq);

    // 2) Grid-split-K MFMA flash attention -> partial O/l
    attn_mfma<<<dim3(Sq / 64, Bq * Nq, 2), blk, 0, stream>>>(
        qkv_bf, vT, mask, opart, lpart);

    // 2b) merge halves -> ctx bf16
    attn_merge<<<dim3((int)(nCtx / 1024)), blk, 0, stream>>>(
        opart, lpart, ctx_bf);

    // 3) Output projection (MFMA) + bias + residual -> x bf16
    gemm_mfma_out<<<dim3(Hq / TN, Mq / TM), blk, 0, stream>>>(
        ctx_bf, Wout_bf, b_out, hidden, x_bf, Mq, Hq, Hq);

    // 4) LayerNorm: bf16 x -> fp32 out
    ln_kernel<<<dim3(Mq), blk, 0, stream>>>(x_bf, gamma, beta, out);
}